// Round 1
// baseline (594.574 us; speedup 1.0000x reference)
//
#include <hip/hip_runtime.h>

// BoxFilter r=8 (k=17), fused separable pass over [8,32,512,512] fp32.
// BARRIER-FREE design: zero __syncthreads in the kernel.
//  - One block = one (image, 128-row strip). grid = 256*4 = 1024 = 4 blocks/CU
//    (LDS 34.8 KB/block -> 4 resident, 16 waves/CU).
//  - Thread tid owns output columns 2*tid, 2*tid+1 for the whole strip.
//  - Horizontal 17-tap: each thread loads its own 18-float window (9 aligned
//    float2 global loads). Neighbor overlap is served by L1 (row = 2 KB,
//    working set ~16 KB/CU); HBM still reads each row once.
//  - Vertical 17-tap: running sum + 17-row horizontal-sum ring in LDS.
//    Ring columns are THREAD-PRIVATE -> no barrier needed, no bank conflicts
//    beyond free 2-way.
//  - Row loop unrolled x2 with register prefetch of the next row; with no
//    barriers there is no vmcnt(0) drain anywhere in the loop.
// Zero padding matches reference; scale 1/289.

#define WW 512
#define HH 512
#define RR 8
#define KK 17
#define TPB 256
#define NSTRIP 4
#define CH (HH / NSTRIP)      // 128 rows per strip
#define NG (CH + 2 * RR)      // 144 row iterations (even -> clean 2x unroll)

struct Row { float2 a[9]; };

// Load 9 float2 covering input cols [c0-8, c0+9] of row rr, zero-padded.
__device__ __forceinline__ void load_row(const float* __restrict__ xi, int rr,
                                         int c0, bool interior, Row& r) {
    if (rr < 0 || rr >= HH) {          // uniform branch (rr same for all lanes)
#pragma unroll
        for (int q = 0; q < 9; ++q) r.a[q] = make_float2(0.f, 0.f);
        return;
    }
    const float* rp = xi + (size_t)rr * WW;
    if (interior) {                    // lanes 4..251: full window in range
#pragma unroll
        for (int q = 0; q < 9; ++q)
            r.a[q] = *(const float2*)(rp + (c0 - RR) + 2 * q);
    } else {                           // 8 edge lanes: per-element guards
#pragma unroll
        for (int q = 0; q < 9; ++q) {
            const int i0 = c0 - RR + 2 * q;
            const int i1 = i0 + 1;
            const float vx = (i0 >= 0 && i0 < WW) ? rp[i0] : 0.f;
            const float vy = (i1 >= 0 && i1 < WW) ? rp[i1] : 0.f;
            r.a[q] = make_float2(vx, vy);
        }
    }
}

__global__ __launch_bounds__(TPB, 4)
void box_nobar(const float* __restrict__ x, float* __restrict__ out) {
    __shared__ float ring[KK][WW];     // 34.8 KB: horizontal-sum history

    const int tid   = threadIdx.x;
    const int img   = blockIdx.x / NSTRIP;
    const int strip = blockIdx.x % NSTRIP;
    const int h0    = strip * CH;

    const float* xi = x   + (size_t)img * (HH * WW);
    float*       oi = out + (size_t)img * (HH * WW);

    const int  c0       = tid * 2;
    const bool interior = (tid >= 4) && (tid <= 251);  // c0-8 >= 0 && c0+9 <= 511

    // zero own ring columns (thread-private -> no barrier)
#pragma unroll
    for (int z = 0; z < KK; ++z)
        *(float2*)&ring[z][c0] = make_float2(0.f, 0.f);

    const float inv = 1.0f / (float)(KK * KK);
    float vs0 = 0.f, vs1 = 0.f;
    int s = 0;

    // per-row compute: 18-float tree sum, two 17-tap sums by single subtract,
    // vertical running sum via ring add/sub, conditional output store.
#define COMPUTE(RW, G)                                                         \
    {                                                                          \
        const float t0 = (RW.a[0].x + RW.a[0].y) + (RW.a[1].x + RW.a[1].y);    \
        const float t1 = (RW.a[2].x + RW.a[2].y) + (RW.a[3].x + RW.a[3].y);    \
        const float t2 = (RW.a[4].x + RW.a[4].y) + (RW.a[5].x + RW.a[5].y);    \
        const float t3 = (RW.a[6].x + RW.a[6].y) + (RW.a[7].x + RW.a[7].y);    \
        const float t4 = RW.a[8].x + RW.a[8].y;                                \
        const float ssum = ((t0 + t1) + (t2 + t3)) + t4;                       \
        const float hs0 = ssum - RW.a[8].y;  /* cols c0-8 .. c0+8 */           \
        const float hs1 = ssum - RW.a[0].x;  /* cols c0-7 .. c0+9 */           \
        const float2 old = *(float2*)&ring[s][c0];                             \
        vs0 += hs0 - old.x;                                                    \
        vs1 += hs1 - old.y;                                                    \
        *(float2*)&ring[s][c0] = make_float2(hs0, hs1);                        \
        if (++s == KK) s = 0;                                                  \
        if ((G) >= 2 * RR) {                                                   \
            const int y = h0 + (G) - 2 * RR;                                   \
            ((float2*)(oi + (size_t)y * WW))[tid] =                            \
                make_float2(vs0 * inv, vs1 * inv);                             \
        }                                                                      \
    }

    Row A, B;
    load_row(xi, h0 - RR, c0, interior, A);

    for (int g = 0; g < NG; g += 2) {
        load_row(xi, h0 - RR + g + 1, c0, interior, B);  // prefetch next row
        COMPUTE(A, g);
        load_row(xi, h0 - RR + g + 2, c0, interior, A);  // prefetch row after
        COMPUTE(B, g + 1);
    }
#undef COMPUTE
}

extern "C" void kernel_launch(void* const* d_in, const int* in_sizes, int n_in,
                              void* d_out, int out_size, void* d_ws, size_t ws_size,
                              hipStream_t stream) {
    const float* x   = (const float*)d_in[0];
    float*       out = (float*)d_out;
    const int nImg = in_sizes[0] / (HH * WW);   // 8*32 = 256 images
    dim3 grid(nImg * NSTRIP), block(TPB);
    box_nobar<<<grid, block, 0, stream>>>(x, out);
}